// Round 13
// baseline (446.359 us; speedup 1.0000x reference)
//
#include <hip/hip_runtime.h>
#include <hip/hip_fp16.h>

#define HID 64
#define BN_EPS 1e-5f
#define WINSH 8          // 256 nodes per dst-window
#define WINSZ 256
#define B1 256           // bucketing blocks
#define PIT 72           // LDS pitch in shorts (16B-aligned fragment reads)

typedef short bf16x8 __attribute__((ext_vector_type(8)));
typedef float f32x4 __attribute__((ext_vector_type(4)));

__device__ __forceinline__ unsigned short f2b(float f) {
    unsigned int u = __float_as_uint(f);
    u = (u + 0x7FFF + ((u >> 16) & 1)) >> 16;   // RNE
    return (unsigned short)u;
}
__device__ __forceinline__ float b2f(unsigned short h) {
    return __uint_as_float(((unsigned int)h) << 16);
}
__device__ __forceinline__ f32x4 mfma_bf16(bf16x8 a, bf16x8 b, f32x4 c) {
    return __builtin_amdgcn_mfma_f32_16x16x32_bf16(a, b, c, 0, 0, 0);
}

// ---------------------------------------------------------------------------
// prep: blocks 0-6 = weight split; block 7 = zero stats; blocks 8+ = histogram
// ---------------------------------------------------------------------------
__global__ __launch_bounds__(256) void prep_kernel(const float* __restrict__ w2a,
                                                   const float* __restrict__ w1s,
                                                   const float* __restrict__ w2s,
                                                   unsigned short* __restrict__ whi,
                                                   unsigned short* __restrict__ wlo,
                                                   float* __restrict__ stats,
                                                   const int* __restrict__ dst,
                                                   int* __restrict__ cnt,
                                                   int E, int nw, int chunk) {
    int blk = blockIdx.x, tid = threadIdx.x;
    if (blk < 7) {
        const float* srcm = (blk == 0) ? w2a : (blk <= 3 ? w1s + (size_t)(blk - 1) * 4096
                                                         : w2s + (size_t)(blk - 4) * 4096);
        unsigned short* dh = whi + (size_t)blk * 4096;
        unsigned short* dl = wlo + (size_t)blk * 4096;
        for (int idx = tid; idx < 4096; idx += 256) {
            int j = idx & 7;
            int lane = (idx >> 3) & 63;
            int ntkh = idx >> 9;
            int nt = ntkh >> 1, kh = ntkh & 1;
            int nc = nt * 16 + (lane & 15);
            int k = kh * 32 + (lane >> 4) * 8 + j;
            float v = srcm[k * 64 + nc];
            unsigned short h = f2b(v);
            dh[idx] = h;
            dl[idx] = f2b(v - b2f(h));
        }
    } else if (blk == 7) {
        stats[tid] = 0.f;
        stats[tid + 256] = 0.f;
    } else {
        __shared__ int c[256];
        int b = blk - 8;
        c[tid] = 0;
        __syncthreads();
        int lo = b * chunk;
        int hi = lo + chunk; if (hi > E) hi = E;
        if ((((size_t)(dst + lo)) & 15) == 0) {
            int n4 = (hi - lo) >> 2;
            const int4* d4p = (const int4*)(dst + lo);
            for (int g = tid; g < n4; g += 256) {
                int4 d4 = d4p[g];
                atomicAdd(&c[d4.x >> WINSH], 1);
                atomicAdd(&c[d4.y >> WINSH], 1);
                atomicAdd(&c[d4.z >> WINSH], 1);
                atomicAdd(&c[d4.w >> WINSH], 1);
            }
            for (int e = lo + (n4 << 2) + tid; e < hi; e += 256)
                atomicAdd(&c[dst[e] >> WINSH], 1);
        } else {
            for (int e = lo + tid; e < hi; e += 256) atomicAdd(&c[dst[e] >> WINSH], 1);
        }
        __syncthreads();
        if (tid < nw) cnt[tid * B1 + b] = c[tid];
    }
}

// ---------------------------------------------------------------------------
// Hierarchical scan; global prefix for cell i = cpart[i] + blockoff[i>>8].
// ---------------------------------------------------------------------------
__global__ __launch_bounds__(256) void scan_a_kernel(const int* __restrict__ in,
                                                     int* __restrict__ partial,
                                                     int* __restrict__ blocksum, int n) {
    __shared__ int sums[256];
    int tid = threadIdx.x;
    int i = blockIdx.x * 256 + tid;
    int v = (i < n) ? in[i] : 0;
    sums[tid] = v;
    __syncthreads();
    for (int off = 1; off < 256; off <<= 1) {
        int t = (tid >= off) ? sums[tid - off] : 0;
        __syncthreads();
        sums[tid] += t;
        __syncthreads();
    }
    if (i < n) partial[i] = sums[tid] - v;
    if (tid == 255) blocksum[blockIdx.x] = sums[255];
}

__global__ __launch_bounds__(256) void scan_b_kernel(const int* __restrict__ blocksum,
                                                     int* __restrict__ blockoff, int nb) {
    __shared__ int s[256];
    __shared__ int carry;
    int tid = threadIdx.x;
    if (tid == 0) carry = 0;
    __syncthreads();
    for (int base = 0; base < nb; base += 256) {
        int i = base + tid;
        int v = (i < nb) ? blocksum[i] : 0;
        s[tid] = v;
        __syncthreads();
        for (int off = 1; off < 256; off <<= 1) {
            int t = (tid >= off) ? s[tid - off] : 0;
            __syncthreads();
            s[tid] += t;
            __syncthreads();
        }
        if (i < nb) blockoff[i] = carry + s[tid] - v;
        __syncthreads();
        if (tid == 0) carry += s[255];
        __syncthreads();
    }
}

__global__ __launch_bounds__(256) void p3_bucket_kernel(const int* __restrict__ src,
                                                        const int* __restrict__ dst,
                                                        const int* __restrict__ cpart,
                                                        const int* __restrict__ blockoff,
                                                        int* __restrict__ ebuf,
                                                        int E, int nw, int chunk) {
    __shared__ int cur[256];
    int tid = threadIdx.x, b = blockIdx.x;
    if (tid < nw) cur[tid] = cpart[tid * B1 + b] + blockoff[tid];
    __syncthreads();
    int lo = b * chunk;
    int hi = lo + chunk; if (hi > E) hi = E;
    if (((((size_t)(dst + lo)) | ((size_t)(src + lo))) & 15) == 0) {
        int n4 = (hi - lo) >> 2;
        const int4* d4p = (const int4*)(dst + lo);
        const int4* s4p = (const int4*)(src + lo);
        for (int g = tid; g < n4; g += 256) {
            int4 d4 = d4p[g];
            int4 s4 = s4p[g];
            int p0 = atomicAdd(&cur[d4.x >> WINSH], 1);
            ebuf[p0] = s4.x | ((d4.x & (WINSZ - 1)) << 24);
            int p1 = atomicAdd(&cur[d4.y >> WINSH], 1);
            ebuf[p1] = s4.y | ((d4.y & (WINSZ - 1)) << 24);
            int p2 = atomicAdd(&cur[d4.z >> WINSH], 1);
            ebuf[p2] = s4.z | ((d4.z & (WINSZ - 1)) << 24);
            int p3 = atomicAdd(&cur[d4.w >> WINSH], 1);
            ebuf[p3] = s4.w | ((d4.w & (WINSZ - 1)) << 24);
        }
        for (int e = lo + (n4 << 2) + tid; e < hi; e += 256) {
            int d = dst[e];
            int pos = atomicAdd(&cur[d >> WINSH], 1);
            ebuf[pos] = src[e] | ((d & (WINSZ - 1)) << 24);
        }
    } else {
        for (int e = lo + tid; e < hi; e += 256) {
            int d = dst[e];
            int pos = atomicAdd(&cur[d >> WINSH], 1);
            ebuf[pos] = src[e] | ((d & (WINSZ - 1)) << 24);
        }
    }
}

__global__ __launch_bounds__(256) void p4_fine_kernel(const int* __restrict__ ebuf,
                                                      const int* __restrict__ cpart,
                                                      const int* __restrict__ blockoff,
                                                      int* __restrict__ csr_src,
                                                      int* __restrict__ rowptr,
                                                      int* __restrict__ deg,
                                                      int E, int n, int nw) {
    __shared__ int fcnt[256];
    __shared__ int foff[256];
    int tid = threadIdx.x, w = blockIdx.x;
    int lo = cpart[w * B1] + blockoff[w];
    int hi = (w + 1 < nw) ? cpart[(w + 1) * B1] + blockoff[w + 1] : E;
    fcnt[tid] = 0;
    __syncthreads();
    for (int e = lo + tid; e < hi; e += 256) atomicAdd(&fcnt[(unsigned)ebuf[e] >> 24], 1);
    __syncthreads();
    int v = fcnt[tid];
    foff[tid] = v;
    __syncthreads();
    for (int off = 1; off < 256; off <<= 1) {
        int t = (tid >= off) ? foff[tid - off] : 0;
        __syncthreads();
        foff[tid] += t;
        __syncthreads();
    }
    int myoff = lo + foff[tid] - v;
    int node = w * WINSZ + tid;
    if (node < n) { rowptr[node] = myoff; deg[node] = v; }
    __syncthreads();
    fcnt[tid] = myoff;
    __syncthreads();
    for (int e = lo + tid; e < hi; e += 256) {
        int p = ebuf[e];
        int pos = atomicAdd(&fcnt[(unsigned)p >> 24], 1);   // LDS atomic
        csr_src[pos] = p & 0xFFFFFF;
    }
}

// ---------------------------------------------------------------------------
// Layer 1 scalar aggregation
// ---------------------------------------------------------------------------
__global__ __launch_bounds__(256) void gather1_kernel(const float* __restrict__ x,
                                                      const int* __restrict__ rowptr,
                                                      const int* __restrict__ deg,
                                                      const int* __restrict__ csr_src,
                                                      const float* __restrict__ eps,
                                                      float* __restrict__ zscalar, int n) {
    int node = blockIdx.x * 4 + (threadIdx.x >> 6);
    int lane = threadIdx.x & 63;
    if (node >= n) return;
    int start = __builtin_amdgcn_readfirstlane(rowptr[node]);
    int cnt   = __builtin_amdgcn_readfirstlane(deg[node]);
    float a = 0.f;
    for (int i = lane; i < cnt; i += 64) a += x[csr_src[start + i]];
    for (int off = 32; off > 0; off >>= 1) a += __shfl_xor(a, off);
    if (lane == 0) zscalar[node] = (1.0f + eps[0]) * x[node] + a;
}

// ---------------------------------------------------------------------------
// gatherz, FEATURE-SPLIT for L2 residency: grid is half-major; each block
// handles 4 nodes for ONE feature-half (32 features = 64B/row -> 3.2 MB
// working set < 4 MB per-XCD L2). Wave = node: fp = lane&15 (feature pair
// within half), q = lane>>4 (4 edge slots, 16-edge unroll = 4 loads in
// flight/lane). Quad's 16 lanes read one contiguous 64B row-half. Reduction
// over quads via shfl_xor(16|32). BN of prev layer computed inline.
// ---------------------------------------------------------------------------
__global__ __launch_bounds__(256) void gatherz_kernel(const __half* __restrict__ hh16,
                                                      const float* __restrict__ stats_prev,
                                                      const float* __restrict__ gamma_prev,
                                                      const float* __restrict__ beta_prev,
                                                      const int* __restrict__ rowptr,
                                                      const int* __restrict__ deg,
                                                      const int* __restrict__ csr_src,
                                                      const float* __restrict__ eps,
                                                      int layer,
                                                      __half* __restrict__ zh16,
                                                      int n, int nblk_half) {
    int bid = blockIdx.x;
    int halfsel = (bid >= nblk_half) ? 1 : 0;
    int node = (bid - halfsel * nblk_half) * 4 + (threadIdx.x >> 6);
    int lane = threadIdx.x & 63;
    int fp = lane & 15;               // feature-pair within half
    int q = lane >> 4;                // edge slot
    int fpg = halfsel * 16 + fp;      // global feature-pair index (0..31)

    // BN params of previous layer for this feature pair
    float inv_n = 1.0f / (float)n;
    float2 sm = ((const float2*)stats_prev)[fpg];
    float2 sq = ((const float2*)(stats_prev + 64))[fpg];
    float2 gm = ((const float2*)gamma_prev)[fpg];
    float2 bt = ((const float2*)beta_prev)[fpg];
    float mux = sm.x * inv_n, muy = sm.y * inv_n;
    float scx = gm.x * rsqrtf(sq.x * inv_n - mux * mux + BN_EPS);
    float scy = gm.y * rsqrtf(sq.y * inv_n - muy * muy + BN_EPS);
    float shx = bt.x - mux * scx;
    float shy = bt.y - muy * scy;

    if (node >= n) return;
    int start = __builtin_amdgcn_readfirstlane(rowptr[node]);
    int cnt   = __builtin_amdgcn_readfirstlane(deg[node]);

    const __half2* hh2 = (const __half2*)hh16;   // row stride 32 half2
    float ax0 = 0.f, ay0 = 0.f, ax1 = 0.f, ay1 = 0.f;
    float ax2 = 0.f, ay2 = 0.f, ax3 = 0.f, ay3 = 0.f;
    int e = 0;
    for (; e + 16 <= cnt; e += 16) {
        int s0 = csr_src[start + e + q];
        int s1 = csr_src[start + e + 4 + q];
        int s2 = csr_src[start + e + 8 + q];
        int s3 = csr_src[start + e + 12 + q];
        float2 v0 = __half22float2(hh2[(size_t)s0 * 32 + fpg]);
        float2 v1 = __half22float2(hh2[(size_t)s1 * 32 + fpg]);
        float2 v2 = __half22float2(hh2[(size_t)s2 * 32 + fpg]);
        float2 v3 = __half22float2(hh2[(size_t)s3 * 32 + fpg]);
        ax0 += v0.x; ay0 += v0.y;
        ax1 += v1.x; ay1 += v1.y;
        ax2 += v2.x; ay2 += v2.y;
        ax3 += v3.x; ay3 += v3.y;
    }
    for (; e < cnt; e += 4) {
        int idx = e + q;
        if (idx < cnt) {
            int s = csr_src[start + idx];
            float2 v = __half22float2(hh2[(size_t)s * 32 + fpg]);
            ax0 += v.x; ay0 += v.y;
        }
    }
    float sx = (ax0 + ax1) + (ax2 + ax3);
    float sy = (ay0 + ay1) + (ay2 + ay3);
    sx += __shfl_xor(sx, 16); sy += __shfl_xor(sy, 16);
    sx += __shfl_xor(sx, 32); sy += __shfl_xor(sy, 32);

    float ep = 1.0f + eps[layer];
    float2 self = __half22float2(hh2[(size_t)node * 32 + fpg]);
    float zx = fmaf(scx, fmaf(ep, self.x, sx), shx * (ep + (float)cnt));
    float zy = fmaf(scy, fmaf(ep, self.y, sy), shy * (ep + (float)cnt));
    if (q == 0) {
        ((__half2*)zh16)[(size_t)node * 32 + fpg] = __floats2half2_rn(zx, zy);
    }
}

// ---------------------------------------------------------------------------
// MFMA MLP, split-bf16 precision (unchanged from R12).
// ---------------------------------------------------------------------------
__global__ __launch_bounds__(256) void mlp_kernel(const __half* __restrict__ zh16,
                                                  const float* __restrict__ zscalar,
                                                  const float* __restrict__ w1a,
                                                  const float* __restrict__ b1a,
                                                  const unsigned short* __restrict__ w1h,
                                                  const unsigned short* __restrict__ w1l,
                                                  const float* __restrict__ b1v,
                                                  const unsigned short* __restrict__ w2h,
                                                  const unsigned short* __restrict__ w2l,
                                                  const float* __restrict__ b2v,
                                                  float* __restrict__ hpre,
                                                  __half* __restrict__ hh16,
                                                  float* __restrict__ stats,
                                                  int n, int mode,
                                                  int write_hpre, int write_hh) {
    __shared__ __align__(16) unsigned short Ah[64 * PIT];
    __shared__ __align__(16) unsigned short Al[64 * PIT];
    __shared__ float ssum[64], ssq[64];

    int tid = threadIdx.x;
    int base = blockIdx.x * 64;

    if (mode) {
        const unsigned int* z32 = (const unsigned int*)zh16;
        for (int i = tid; i < 2048; i += 256) {
            int nn = i >> 5, c = i & 31;
            unsigned int u = z32[(size_t)(base + nn) * 32 + c];
            __half2 hv = *(__half2*)&u;
            float vx = __half2float(hv.x);
            float vy = __half2float(hv.y);
            unsigned short hx = f2b(vx);
            unsigned short hy = f2b(vy);
            Ah[nn * PIT + 2 * c]     = hx;
            Ah[nn * PIT + 2 * c + 1] = hy;
            Al[nn * PIT + 2 * c]     = f2b(vx - b2f(hx));
            Al[nn * PIT + 2 * c + 1] = f2b(vy - b2f(hy));
        }
    } else {
        for (int i = tid; i < 4096; i += 256) {
            int nn = i >> 6, k = i & 63;
            float zv = zscalar[base + nn];
            float v = fmaxf(fmaf(zv, w1a[k], b1a[k]), 0.f);
            unsigned short h = f2b(v);
            Ah[nn * PIT + k] = h;
            Al[nn * PIT + k] = f2b(v - b2f(h));
        }
    }
    if (tid < 64) { ssum[tid] = 0.f; ssq[tid] = 0.f; }
    __syncthreads();

    int l = tid & 63;
    int m = l & 15;            // A/B free index; D col
    int q = l >> 4;            // quad; D row block
    int m0 = (tid >> 6) * 16;  // wave's node-row block

    const bf16x8* a0h = (const bf16x8*)&Ah[(m0 + m) * PIT + q * 8];
    const bf16x8* a1h = (const bf16x8*)&Ah[(m0 + m) * PIT + 32 + q * 8];
    const bf16x8* a0l = (const bf16x8*)&Al[(m0 + m) * PIT + q * 8];
    const bf16x8* a1l = (const bf16x8*)&Al[(m0 + m) * PIT + 32 + q * 8];

    if (mode) {
        // GEMM1: T = relu(Z @ W1 + b1), split arithmetic
        bf16x8 xa0h = *a0h, xa1h = *a1h, xa0l = *a0l, xa1l = *a1l;
        f32x4 acc[4];
#pragma unroll
        for (int nt = 0; nt < 4; ++nt) {
            size_t fo0 = ((size_t)(nt * 2 + 0) * 64 + l) * 8;
            size_t fo1 = ((size_t)(nt * 2 + 1) * 64 + l) * 8;
            bf16x8 b0h = *(const bf16x8*)(w1h + fo0);
            bf16x8 b1h_ = *(const bf16x8*)(w1h + fo1);
            bf16x8 b0l = *(const bf16x8*)(w1l + fo0);
            bf16x8 b1l_ = *(const bf16x8*)(w1l + fo1);
            f32x4 c = {0.f, 0.f, 0.f, 0.f};
            c = mfma_bf16(xa0h, b0h, c);
            c = mfma_bf16(xa0h, b0l, c);
            c = mfma_bf16(xa0l, b0h, c);
            c = mfma_bf16(xa1h, b1h_, c);
            c = mfma_bf16(xa1h, b1l_, c);
            c = mfma_bf16(xa1l, b1h_, c);
            acc[nt] = c;
        }
#pragma unroll
        for (int nt = 0; nt < 4; ++nt) {
            int col = nt * 16 + m;
            float bv = b1v[col];
#pragma unroll
            for (int r = 0; r < 4; ++r) {
                int row = m0 + q * 4 + r;
                float T = fmaxf(acc[nt][r] + bv, 0.f);
                unsigned short h = f2b(T);
                Ah[row * PIT + col] = h;
                Al[row * PIT + col] = f2b(T - b2f(h));
            }
        }
    }
    __syncthreads();

    // GEMM2: H = relu(T @ W2 + b2), split arithmetic
    {
        bf16x8 xa0h = *a0h, xa1h = *a1h, xa0l = *a0l, xa1l = *a1l;
        f32x4 acc[4];
#pragma unroll
        for (int nt = 0; nt < 4; ++nt) {
            size_t fo0 = ((size_t)(nt * 2 + 0) * 64 + l) * 8;
            size_t fo1 = ((size_t)(nt * 2 + 1) * 64 + l) * 8;
            bf16x8 b0h = *(const bf16x8*)(w2h + fo0);
            bf16x8 b1h_ = *(const bf16x8*)(w2h + fo1);
            bf16x8 b0l = *(const bf16x8*)(w2l + fo0);
            bf16x8 b1l_ = *(const bf16x8*)(w2l + fo1);
            f32x4 c = {0.f, 0.f, 0.f, 0.f};
            c = mfma_bf16(xa0h, b0h, c);
            c = mfma_bf16(xa0h, b0l, c);
            c = mfma_bf16(xa0l, b0h, c);
            c = mfma_bf16(xa1h, b1h_, c);
            c = mfma_bf16(xa1h, b1l_, c);
            c = mfma_bf16(xa1l, b1h_, c);
            acc[nt] = c;
        }
#pragma unroll
        for (int nt = 0; nt < 4; ++nt) {
            int col = nt * 16 + m;
            float bv = b2v[col];
            float cs = 0.f, cq = 0.f;
#pragma unroll
            for (int r = 0; r < 4; ++r) {
                int node = base + m0 + q * 4 + r;
                float h = fmaxf(acc[nt][r] + bv, 0.f);
                if (node < n) {
                    if (write_hpre) hpre[(size_t)node * HID + col] = h;
                    if (write_hh) hh16[(size_t)node * HID + col] = __float2half(h);
                    cs += h;
                    cq = fmaf(h, h, cq);
                }
            }
            cs += __shfl_xor(cs, 16); cs += __shfl_xor(cs, 32);
            cq += __shfl_xor(cq, 16); cq += __shfl_xor(cq, 32);
            if (q == 0) {
                atomicAdd(&ssum[col], cs);
                atomicAdd(&ssq[col], cq);
            }
        }
    }
    __syncthreads();
    if (tid < 64) {
        atomicAdd(&stats[tid], ssum[tid]);
        atomicAdd(&stats[64 + tid], ssq[tid]);
    }
}

// ---------------------------------------------------------------------------
// Final: BN of layer 4 from stats + fc dot.
// ---------------------------------------------------------------------------
__global__ __launch_bounds__(256) void final_kernel(const float* __restrict__ hpre,
                                                    const float* __restrict__ stats,
                                                    const float* __restrict__ gamma,
                                                    const float* __restrict__ beta,
                                                    const float* __restrict__ fcw,
                                                    const float* __restrict__ fcb,
                                                    float* __restrict__ out, int n) {
    int wave = threadIdx.x >> 6;
    int lane = threadIdx.x & 63;
    int node = blockIdx.x * 4 + wave;
    if (node < n) {
        float inv_n = 1.0f / (float)n;
        float mu = stats[lane] * inv_n;
        float var = stats[64 + lane] * inv_n - mu * mu;
        float inv = rsqrtf(var + BN_EPS);
        float sc = gamma[lane] * inv;
        float sh = beta[lane] - mu * sc;
        float v = hpre[(size_t)node * HID + lane];
        float t = fmaf(v, sc, sh) * fcw[lane];
        for (int off = 32; off > 0; off >>= 1) t += __shfl_xor(t, off);
        if (lane == 0) out[node] = t + fcb[0];
    }
}

// ---------------------------------------------------------------------------
extern "C" void kernel_launch(void* const* d_in, const int* in_sizes, int n_in,
                              void* d_out, int out_size, void* d_ws, size_t ws_size,
                              hipStream_t stream) {
    const float* x      = (const float*)d_in[0];
    const int*   ei     = (const int*)d_in[1];
    const float* w1a    = (const float*)d_in[2];
    const float* b1a    = (const float*)d_in[3];
    const float* w2a    = (const float*)d_in[4];
    const float* b2a    = (const float*)d_in[5];
    const float* w1s    = (const float*)d_in[6];
    const float* b1s    = (const float*)d_in[7];
    const float* w2s    = (const float*)d_in[8];
    const float* b2s    = (const float*)d_in[9];
    const float* eps    = (const float*)d_in[10];
    const float* gammas = (const float*)d_in[11];
    const float* betas  = (const float*)d_in[12];
    const float* fcw    = (const float*)d_in[13];
    const float* fcb    = (const float*)d_in[14];
    float* out = (float*)d_out;

    int n = in_sizes[0];          // 50000
    int E = in_sizes[1] / 2;      // 1600000
    int npad = ((n + 63) / 64) * 64;
    int nblk = npad / 64;

    int nw = (n + WINSZ - 1) >> WINSH;      // 196 windows
    int NWB = nw * B1;
    int chunk = (((E + B1 - 1) / B1) + 3) & ~3;   // 4-aligned for int4 path
    int nbs2 = (NWB + 255) / 256;

    const int* src = ei;
    const int* dst = ei + E;

    char* p = (char*)d_ws;
    float* csrtmp  = (float*)p; p += (size_t)npad * HID * 4;   // CSR temps region
    float* hpre    = (float*)p; p += (size_t)npad * HID * 4;
    __half* hh16   = (__half*)p; p += (size_t)npad * HID * 2;
    __half* zh16   = (__half*)p; p += (size_t)npad * HID * 2;
    float* zscalar = (float*)p; p += (size_t)npad * 4;
    float* stats   = (float*)p; p += 4 * 128 * 4;
    unsigned short* whi = (unsigned short*)p; p += 7 * 4096 * 2;
    unsigned short* wlo = (unsigned short*)p; p += 7 * 4096 * 2;
    int* deg     = (int*)p; p += (size_t)n * 4;
    int* rowptr  = (int*)p; p += (size_t)n * 4;
    int* csr_src = (int*)p; p += (size_t)E * 4;

    // CSR-build temporaries live in csrtmp (dead after p4)
    int* ebuf     = (int*)csrtmp;
    int* cnt      = ebuf + E;
    int* cpart    = cnt + NWB;
    int* bsum     = cpart + NWB;
    int* blockoff = bsum + nbs2;

    // ---- prep (weights + stats zero + histogram) + CSR build ----
    prep_kernel<<<8 + B1, 256, 0, stream>>>(w2a, w1s, w2s, whi, wlo, stats,
                                            dst, cnt, E, nw, chunk);
    scan_a_kernel<<<nbs2, 256, 0, stream>>>(cnt, cpart, bsum, NWB);
    scan_b_kernel<<<1, 256, 0, stream>>>(bsum, blockoff, nbs2);
    p3_bucket_kernel<<<B1, 256, 0, stream>>>(src, dst, cpart, blockoff, ebuf, E, nw, chunk);
    p4_fine_kernel<<<nw, 256, 0, stream>>>(ebuf, cpart, blockoff, csr_src, rowptr, deg,
                                           E, n, nw);

    // ---- Layer 1 (1 -> 64 -> 64): writes fp16 mirror only ----
    gather1_kernel<<<(n + 3) / 4, 256, 0, stream>>>(x, rowptr, deg, csr_src, eps, zscalar, n);
    mlp_kernel<<<nblk, 256, 0, stream>>>(zh16, zscalar, w1a, b1a,
                                         whi, wlo, b1a /*unused*/,
                                         whi /*slot0=w2a*/, wlo, b2a,
                                         hpre, hh16, stats, n, 0,
                                         /*write_hpre=*/0, /*write_hh=*/1);

    // ---- Layers 2-4: feature-split gatherz (fp16 in/out) + MLP ----
    int nblk_half = (n + 3) / 4;
    for (int l = 1; l <= 3; ++l) {
        gatherz_kernel<<<2 * nblk_half, 256, 0, stream>>>(hh16,
                                                          stats + (l - 1) * 128,
                                                          gammas + (l - 1) * HID,
                                                          betas + (l - 1) * HID,
                                                          rowptr, deg, csr_src, eps, l,
                                                          zh16, n, nblk_half);
        mlp_kernel<<<nblk, 256, 0, stream>>>(zh16, zscalar, w1a, b1a,
                                             whi + (size_t)l * 4096,
                                             wlo + (size_t)l * 4096,
                                             b1s + (size_t)(l - 1) * HID,
                                             whi + (size_t)(3 + l) * 4096,
                                             wlo + (size_t)(3 + l) * 4096,
                                             b2s + (size_t)(l - 1) * HID,
                                             hpre, hh16, stats + l * 128,
                                             n, 1,
                                             /*write_hpre=*/(l == 3) ? 1 : 0,
                                             /*write_hh=*/(l < 3) ? 1 : 0);
    }
    final_kernel<<<(n + 3) / 4, 256, 0, stream>>>(hpre, stats + 3 * 128,
                                                  gammas + 3 * HID, betas + 3 * HID,
                                                  fcw, fcb, out, n);
}

// Round 14
// 374.562 us; speedup vs baseline: 1.1917x; 1.1917x over previous
//
#include <hip/hip_runtime.h>
#include <hip/hip_fp16.h>

#define HID 64
#define BN_EPS 1e-5f
#define WINSH 8          // 256 nodes per dst-window
#define WINSZ 256
#define B1 256           // bucketing blocks
#define PIT 72           // LDS pitch in shorts (16B-aligned fragment reads)

typedef short bf16x8 __attribute__((ext_vector_type(8)));
typedef float f32x4 __attribute__((ext_vector_type(4)));

__device__ __forceinline__ unsigned short f2b(float f) {
    unsigned int u = __float_as_uint(f);
    u = (u + 0x7FFF + ((u >> 16) & 1)) >> 16;   // RNE
    return (unsigned short)u;
}
__device__ __forceinline__ float b2f(unsigned short h) {
    return __uint_as_float(((unsigned int)h) << 16);
}
__device__ __forceinline__ f32x4 mfma_bf16(bf16x8 a, bf16x8 b, f32x4 c) {
    return __builtin_amdgcn_mfma_f32_16x16x32_bf16(a, b, c, 0, 0, 0);
}

// ---------------------------------------------------------------------------
// prep: blocks 0-6 = weight split; block 7 = zero stats; blocks 8+ = histogram
// ---------------------------------------------------------------------------
__global__ __launch_bounds__(256) void prep_kernel(const float* __restrict__ w2a,
                                                   const float* __restrict__ w1s,
                                                   const float* __restrict__ w2s,
                                                   unsigned short* __restrict__ whi,
                                                   unsigned short* __restrict__ wlo,
                                                   float* __restrict__ stats,
                                                   const int* __restrict__ dst,
                                                   int* __restrict__ cnt,
                                                   int E, int nw, int chunk) {
    int blk = blockIdx.x, tid = threadIdx.x;
    if (blk < 7) {
        const float* srcm = (blk == 0) ? w2a : (blk <= 3 ? w1s + (size_t)(blk - 1) * 4096
                                                         : w2s + (size_t)(blk - 4) * 4096);
        unsigned short* dh = whi + (size_t)blk * 4096;
        unsigned short* dl = wlo + (size_t)blk * 4096;
        for (int idx = tid; idx < 4096; idx += 256) {
            int j = idx & 7;
            int lane = (idx >> 3) & 63;
            int ntkh = idx >> 9;
            int nt = ntkh >> 1, kh = ntkh & 1;
            int nc = nt * 16 + (lane & 15);
            int k = kh * 32 + (lane >> 4) * 8 + j;
            float v = srcm[k * 64 + nc];
            unsigned short h = f2b(v);
            dh[idx] = h;
            dl[idx] = f2b(v - b2f(h));
        }
    } else if (blk == 7) {
        stats[tid] = 0.f;
        stats[tid + 256] = 0.f;
    } else {
        __shared__ int c[256];
        int b = blk - 8;
        c[tid] = 0;
        __syncthreads();
        int lo = b * chunk;
        int hi = lo + chunk; if (hi > E) hi = E;
        if ((((size_t)(dst + lo)) & 15) == 0) {
            int n4 = (hi - lo) >> 2;
            const int4* d4p = (const int4*)(dst + lo);
            for (int g = tid; g < n4; g += 256) {
                int4 d4 = d4p[g];
                atomicAdd(&c[d4.x >> WINSH], 1);
                atomicAdd(&c[d4.y >> WINSH], 1);
                atomicAdd(&c[d4.z >> WINSH], 1);
                atomicAdd(&c[d4.w >> WINSH], 1);
            }
            for (int e = lo + (n4 << 2) + tid; e < hi; e += 256)
                atomicAdd(&c[dst[e] >> WINSH], 1);
        } else {
            for (int e = lo + tid; e < hi; e += 256) atomicAdd(&c[dst[e] >> WINSH], 1);
        }
        __syncthreads();
        if (tid < nw) cnt[tid * B1 + b] = c[tid];
    }
}

// ---------------------------------------------------------------------------
// Hierarchical scan; global prefix for cell i = cpart[i] + blockoff[i>>8].
// ---------------------------------------------------------------------------
__global__ __launch_bounds__(256) void scan_a_kernel(const int* __restrict__ in,
                                                     int* __restrict__ partial,
                                                     int* __restrict__ blocksum, int n) {
    __shared__ int sums[256];
    int tid = threadIdx.x;
    int i = blockIdx.x * 256 + tid;
    int v = (i < n) ? in[i] : 0;
    sums[tid] = v;
    __syncthreads();
    for (int off = 1; off < 256; off <<= 1) {
        int t = (tid >= off) ? sums[tid - off] : 0;
        __syncthreads();
        sums[tid] += t;
        __syncthreads();
    }
    if (i < n) partial[i] = sums[tid] - v;
    if (tid == 255) blocksum[blockIdx.x] = sums[255];
}

__global__ __launch_bounds__(256) void scan_b_kernel(const int* __restrict__ blocksum,
                                                     int* __restrict__ blockoff, int nb) {
    __shared__ int s[256];
    __shared__ int carry;
    int tid = threadIdx.x;
    if (tid == 0) carry = 0;
    __syncthreads();
    for (int base = 0; base < nb; base += 256) {
        int i = base + tid;
        int v = (i < nb) ? blocksum[i] : 0;
        s[tid] = v;
        __syncthreads();
        for (int off = 1; off < 256; off <<= 1) {
            int t = (tid >= off) ? s[tid - off] : 0;
            __syncthreads();
            s[tid] += t;
            __syncthreads();
        }
        if (i < nb) blockoff[i] = carry + s[tid] - v;
        __syncthreads();
        if (tid == 0) carry += s[255];
        __syncthreads();
    }
}

__global__ __launch_bounds__(256) void p3_bucket_kernel(const int* __restrict__ src,
                                                        const int* __restrict__ dst,
                                                        const int* __restrict__ cpart,
                                                        const int* __restrict__ blockoff,
                                                        int* __restrict__ ebuf,
                                                        int E, int nw, int chunk) {
    __shared__ int cur[256];
    int tid = threadIdx.x, b = blockIdx.x;
    if (tid < nw) cur[tid] = cpart[tid * B1 + b] + blockoff[tid];
    __syncthreads();
    int lo = b * chunk;
    int hi = lo + chunk; if (hi > E) hi = E;
    if (((((size_t)(dst + lo)) | ((size_t)(src + lo))) & 15) == 0) {
        int n4 = (hi - lo) >> 2;
        const int4* d4p = (const int4*)(dst + lo);
        const int4* s4p = (const int4*)(src + lo);
        for (int g = tid; g < n4; g += 256) {
            int4 d4 = d4p[g];
            int4 s4 = s4p[g];
            int p0 = atomicAdd(&cur[d4.x >> WINSH], 1);
            ebuf[p0] = s4.x | ((d4.x & (WINSZ - 1)) << 24);
            int p1 = atomicAdd(&cur[d4.y >> WINSH], 1);
            ebuf[p1] = s4.y | ((d4.y & (WINSZ - 1)) << 24);
            int p2 = atomicAdd(&cur[d4.z >> WINSH], 1);
            ebuf[p2] = s4.z | ((d4.z & (WINSZ - 1)) << 24);
            int p3 = atomicAdd(&cur[d4.w >> WINSH], 1);
            ebuf[p3] = s4.w | ((d4.w & (WINSZ - 1)) << 24);
        }
        for (int e = lo + (n4 << 2) + tid; e < hi; e += 256) {
            int d = dst[e];
            int pos = atomicAdd(&cur[d >> WINSH], 1);
            ebuf[pos] = src[e] | ((d & (WINSZ - 1)) << 24);
        }
    } else {
        for (int e = lo + tid; e < hi; e += 256) {
            int d = dst[e];
            int pos = atomicAdd(&cur[d >> WINSH], 1);
            ebuf[pos] = src[e] | ((d & (WINSZ - 1)) << 24);
        }
    }
}

__global__ __launch_bounds__(256) void p4_fine_kernel(const int* __restrict__ ebuf,
                                                      const int* __restrict__ cpart,
                                                      const int* __restrict__ blockoff,
                                                      int* __restrict__ csr_src,
                                                      int* __restrict__ rowptr,
                                                      int* __restrict__ deg,
                                                      int E, int n, int nw) {
    __shared__ int fcnt[256];
    __shared__ int foff[256];
    int tid = threadIdx.x, w = blockIdx.x;
    int lo = cpart[w * B1] + blockoff[w];
    int hi = (w + 1 < nw) ? cpart[(w + 1) * B1] + blockoff[w + 1] : E;
    fcnt[tid] = 0;
    __syncthreads();
    for (int e = lo + tid; e < hi; e += 256) atomicAdd(&fcnt[(unsigned)ebuf[e] >> 24], 1);
    __syncthreads();
    int v = fcnt[tid];
    foff[tid] = v;
    __syncthreads();
    for (int off = 1; off < 256; off <<= 1) {
        int t = (tid >= off) ? foff[tid - off] : 0;
        __syncthreads();
        foff[tid] += t;
        __syncthreads();
    }
    int myoff = lo + foff[tid] - v;
    int node = w * WINSZ + tid;
    if (node < n) { rowptr[node] = myoff; deg[node] = v; }
    __syncthreads();
    fcnt[tid] = myoff;
    __syncthreads();
    for (int e = lo + tid; e < hi; e += 256) {
        int p = ebuf[e];
        int pos = atomicAdd(&fcnt[(unsigned)p >> 24], 1);   // LDS atomic
        csr_src[pos] = p & 0xFFFFFF;
    }
}

// ---------------------------------------------------------------------------
// Layer 1 scalar aggregation
// ---------------------------------------------------------------------------
__global__ __launch_bounds__(256) void gather1_kernel(const float* __restrict__ x,
                                                      const int* __restrict__ rowptr,
                                                      const int* __restrict__ deg,
                                                      const int* __restrict__ csr_src,
                                                      const float* __restrict__ eps,
                                                      float* __restrict__ zscalar, int n) {
    int node = blockIdx.x * 4 + (threadIdx.x >> 6);
    int lane = threadIdx.x & 63;
    if (node >= n) return;
    int start = __builtin_amdgcn_readfirstlane(rowptr[node]);
    int cnt   = __builtin_amdgcn_readfirstlane(deg[node]);
    float a = 0.f;
    for (int i = lane; i < cnt; i += 64) a += x[csr_src[start + i]];
    for (int off = 32; off > 0; off >>= 1) a += __shfl_xor(a, off);
    if (lane == 0) zscalar[node] = (1.0f + eps[0]) * x[node] + a;
}

// ---------------------------------------------------------------------------
// gatherz (R12 structure): half2 datapath, whole 128B rows (one cache line),
// self term from fp16 mirror, fp16 z output. BN of prev layer inline.
// ---------------------------------------------------------------------------
__global__ __launch_bounds__(256) void gatherz_kernel(const __half* __restrict__ hh16,
                                                      const float* __restrict__ stats_prev,
                                                      const float* __restrict__ gamma_prev,
                                                      const float* __restrict__ beta_prev,
                                                      const int* __restrict__ rowptr,
                                                      const int* __restrict__ deg,
                                                      const int* __restrict__ csr_src,
                                                      const float* __restrict__ eps,
                                                      int layer,
                                                      __half* __restrict__ zh16, int n) {
    int lane = threadIdx.x & 63;
    int half = lane >> 5;          // 0: even rows, 1: odd rows
    int fp = lane & 31;            // feature-pair index (features 2fp, 2fp+1)
    int node = blockIdx.x * 4 + (threadIdx.x >> 6);

    // BN params of previous layer for this feature pair
    float inv_n = 1.0f / (float)n;
    float2 sm = ((const float2*)stats_prev)[fp];
    float2 sq = ((const float2*)(stats_prev + 64))[fp];
    float2 gm = ((const float2*)gamma_prev)[fp];
    float2 bt = ((const float2*)beta_prev)[fp];
    float mux = sm.x * inv_n, muy = sm.y * inv_n;
    float scx = gm.x * rsqrtf(sq.x * inv_n - mux * mux + BN_EPS);
    float scy = gm.y * rsqrtf(sq.y * inv_n - muy * muy + BN_EPS);
    float shx = bt.x - mux * scx;
    float shy = bt.y - muy * scy;

    if (node >= n) return;
    int start = __builtin_amdgcn_readfirstlane(rowptr[node]);
    int cnt   = __builtin_amdgcn_readfirstlane(deg[node]);

    const __half2* hh2 = (const __half2*)hh16;   // row stride 32 half2
    float ax0 = 0.f, ay0 = 0.f, ax1 = 0.f, ay1 = 0.f;
    float ax2 = 0.f, ay2 = 0.f, ax3 = 0.f, ay3 = 0.f;
    int e = 0;
    for (; e + 8 <= cnt; e += 8) {
        int s0 = csr_src[start + e + 0];
        int s1 = csr_src[start + e + 1];
        int s2 = csr_src[start + e + 2];
        int s3 = csr_src[start + e + 3];
        int s4 = csr_src[start + e + 4];
        int s5 = csr_src[start + e + 5];
        int s6 = csr_src[start + e + 6];
        int s7 = csr_src[start + e + 7];
        int r0 = half ? s1 : s0;
        int r1 = half ? s3 : s2;
        int r2 = half ? s5 : s4;
        int r3 = half ? s7 : s6;
        float2 v0 = __half22float2(hh2[(size_t)r0 * 32 + fp]);
        float2 v1 = __half22float2(hh2[(size_t)r1 * 32 + fp]);
        float2 v2 = __half22float2(hh2[(size_t)r2 * 32 + fp]);
        float2 v3 = __half22float2(hh2[(size_t)r3 * 32 + fp]);
        ax0 += v0.x; ay0 += v0.y;
        ax1 += v1.x; ay1 += v1.y;
        ax2 += v2.x; ay2 += v2.y;
        ax3 += v3.x; ay3 += v3.y;
    }
    for (; e < cnt; e += 2) {
        int idx = e + half;
        if (idx < cnt) {
            int s = csr_src[start + idx];
            float2 v = __half22float2(hh2[(size_t)s * 32 + fp]);
            ax0 += v.x; ay0 += v.y;
        }
    }
    float sx = (ax0 + ax1) + (ax2 + ax3);
    float sy = (ay0 + ay1) + (ay2 + ay3);
    sx += __shfl_xor(sx, 32);
    sy += __shfl_xor(sy, 32);

    float ep = 1.0f + eps[layer];
    float2 self = __half22float2(hh2[(size_t)node * 32 + fp]);
    float zx = fmaf(scx, fmaf(ep, self.x, sx), shx * (ep + (float)cnt));
    float zy = fmaf(scy, fmaf(ep, self.y, sy), shy * (ep + (float)cnt));
    if (half == 0) {
        ((__half2*)zh16)[(size_t)node * 32 + fp] = __floats2half2_rn(zx, zy);
    }
}

// ---------------------------------------------------------------------------
// MFMA MLP, split-bf16 precision. mode 1 stages from fp16 z (exact split of
// the fp16 value). Epilogue writes hh16 (layers 1-3) and/or hpre (layer 4).
// ---------------------------------------------------------------------------
__global__ __launch_bounds__(256) void mlp_kernel(const __half* __restrict__ zh16,
                                                  const float* __restrict__ zscalar,
                                                  const float* __restrict__ w1a,
                                                  const float* __restrict__ b1a,
                                                  const unsigned short* __restrict__ w1h,
                                                  const unsigned short* __restrict__ w1l,
                                                  const float* __restrict__ b1v,
                                                  const unsigned short* __restrict__ w2h,
                                                  const unsigned short* __restrict__ w2l,
                                                  const float* __restrict__ b2v,
                                                  float* __restrict__ hpre,
                                                  __half* __restrict__ hh16,
                                                  float* __restrict__ stats,
                                                  int n, int mode,
                                                  int write_hpre, int write_hh) {
    __shared__ __align__(16) unsigned short Ah[64 * PIT];
    __shared__ __align__(16) unsigned short Al[64 * PIT];
    __shared__ float ssum[64], ssq[64];

    int tid = threadIdx.x;
    int base = blockIdx.x * 64;

    if (mode) {
        const unsigned int* z32 = (const unsigned int*)zh16;
        for (int i = tid; i < 2048; i += 256) {
            int nn = i >> 5, c = i & 31;
            unsigned int u = z32[(size_t)(base + nn) * 32 + c];
            __half2 hv = *(__half2*)&u;
            float vx = __half2float(hv.x);
            float vy = __half2float(hv.y);
            unsigned short hx = f2b(vx);
            unsigned short hy = f2b(vy);
            Ah[nn * PIT + 2 * c]     = hx;
            Ah[nn * PIT + 2 * c + 1] = hy;
            Al[nn * PIT + 2 * c]     = f2b(vx - b2f(hx));
            Al[nn * PIT + 2 * c + 1] = f2b(vy - b2f(hy));
        }
    } else {
        for (int i = tid; i < 4096; i += 256) {
            int nn = i >> 6, k = i & 63;
            float zv = zscalar[base + nn];
            float v = fmaxf(fmaf(zv, w1a[k], b1a[k]), 0.f);
            unsigned short h = f2b(v);
            Ah[nn * PIT + k] = h;
            Al[nn * PIT + k] = f2b(v - b2f(h));
        }
    }
    if (tid < 64) { ssum[tid] = 0.f; ssq[tid] = 0.f; }
    __syncthreads();

    int l = tid & 63;
    int m = l & 15;            // A/B free index; D col
    int q = l >> 4;            // quad; D row block
    int m0 = (tid >> 6) * 16;  // wave's node-row block

    const bf16x8* a0h = (const bf16x8*)&Ah[(m0 + m) * PIT + q * 8];
    const bf16x8* a1h = (const bf16x8*)&Ah[(m0 + m) * PIT + 32 + q * 8];
    const bf16x8* a0l = (const bf16x8*)&Al[(m0 + m) * PIT + q * 8];
    const bf16x8* a1l = (const bf16x8*)&Al[(m0 + m) * PIT + 32 + q * 8];

    if (mode) {
        // GEMM1: T = relu(Z @ W1 + b1), split arithmetic
        bf16x8 xa0h = *a0h, xa1h = *a1h, xa0l = *a0l, xa1l = *a1l;
        f32x4 acc[4];
#pragma unroll
        for (int nt = 0; nt < 4; ++nt) {
            size_t fo0 = ((size_t)(nt * 2 + 0) * 64 + l) * 8;
            size_t fo1 = ((size_t)(nt * 2 + 1) * 64 + l) * 8;
            bf16x8 b0h = *(const bf16x8*)(w1h + fo0);
            bf16x8 b1h_ = *(const bf16x8*)(w1h + fo1);
            bf16x8 b0l = *(const bf16x8*)(w1l + fo0);
            bf16x8 b1l_ = *(const bf16x8*)(w1l + fo1);
            f32x4 c = {0.f, 0.f, 0.f, 0.f};
            c = mfma_bf16(xa0h, b0h, c);
            c = mfma_bf16(xa0h, b0l, c);
            c = mfma_bf16(xa0l, b0h, c);
            c = mfma_bf16(xa1h, b1h_, c);
            c = mfma_bf16(xa1h, b1l_, c);
            c = mfma_bf16(xa1l, b1h_, c);
            acc[nt] = c;
        }
#pragma unroll
        for (int nt = 0; nt < 4; ++nt) {
            int col = nt * 16 + m;
            float bv = b1v[col];
#pragma unroll
            for (int r = 0; r < 4; ++r) {
                int row = m0 + q * 4 + r;
                float T = fmaxf(acc[nt][r] + bv, 0.f);
                unsigned short h = f2b(T);
                Ah[row * PIT + col] = h;
                Al[row * PIT + col] = f2b(T - b2f(h));
            }
        }
    }
    __syncthreads();

    // GEMM2: H = relu(T @ W2 + b2), split arithmetic
    {
        bf16x8 xa0h = *a0h, xa1h = *a1h, xa0l = *a0l, xa1l = *a1l;
        f32x4 acc[4];
#pragma unroll
        for (int nt = 0; nt < 4; ++nt) {
            size_t fo0 = ((size_t)(nt * 2 + 0) * 64 + l) * 8;
            size_t fo1 = ((size_t)(nt * 2 + 1) * 64 + l) * 8;
            bf16x8 b0h = *(const bf16x8*)(w2h + fo0);
            bf16x8 b1h_ = *(const bf16x8*)(w2h + fo1);
            bf16x8 b0l = *(const bf16x8*)(w2l + fo0);
            bf16x8 b1l_ = *(const bf16x8*)(w2l + fo1);
            f32x4 c = {0.f, 0.f, 0.f, 0.f};
            c = mfma_bf16(xa0h, b0h, c);
            c = mfma_bf16(xa0h, b0l, c);
            c = mfma_bf16(xa0l, b0h, c);
            c = mfma_bf16(xa1h, b1h_, c);
            c = mfma_bf16(xa1h, b1l_, c);
            c = mfma_bf16(xa1l, b1h_, c);
            acc[nt] = c;
        }
#pragma unroll
        for (int nt = 0; nt < 4; ++nt) {
            int col = nt * 16 + m;
            float bv = b2v[col];
            float cs = 0.f, cq = 0.f;
#pragma unroll
            for (int r = 0; r < 4; ++r) {
                int node = base + m0 + q * 4 + r;
                float h = fmaxf(acc[nt][r] + bv, 0.f);
                if (node < n) {
                    if (write_hpre) hpre[(size_t)node * HID + col] = h;
                    if (write_hh) hh16[(size_t)node * HID + col] = __float2half(h);
                    cs += h;
                    cq = fmaf(h, h, cq);
                }
            }
            cs += __shfl_xor(cs, 16); cs += __shfl_xor(cs, 32);
            cq += __shfl_xor(cq, 16); cq += __shfl_xor(cq, 32);
            if (q == 0) {
                atomicAdd(&ssum[col], cs);
                atomicAdd(&ssq[col], cq);
            }
        }
    }
    __syncthreads();
    if (tid < 64) {
        atomicAdd(&stats[tid], ssum[tid]);
        atomicAdd(&stats[64 + tid], ssq[tid]);
    }
}

// ---------------------------------------------------------------------------
// Final: BN of layer 4 from stats + fc dot.
// ---------------------------------------------------------------------------
__global__ __launch_bounds__(256) void final_kernel(const float* __restrict__ hpre,
                                                    const float* __restrict__ stats,
                                                    const float* __restrict__ gamma,
                                                    const float* __restrict__ beta,
                                                    const float* __restrict__ fcw,
                                                    const float* __restrict__ fcb,
                                                    float* __restrict__ out, int n) {
    int wave = threadIdx.x >> 6;
    int lane = threadIdx.x & 63;
    int node = blockIdx.x * 4 + wave;
    if (node < n) {
        float inv_n = 1.0f / (float)n;
        float mu = stats[lane] * inv_n;
        float var = stats[64 + lane] * inv_n - mu * mu;
        float inv = rsqrtf(var + BN_EPS);
        float sc = gamma[lane] * inv;
        float sh = beta[lane] - mu * sc;
        float v = hpre[(size_t)node * HID + lane];
        float t = fmaf(v, sc, sh) * fcw[lane];
        for (int off = 32; off > 0; off >>= 1) t += __shfl_xor(t, off);
        if (lane == 0) out[node] = t + fcb[0];
    }
}

// ---------------------------------------------------------------------------
extern "C" void kernel_launch(void* const* d_in, const int* in_sizes, int n_in,
                              void* d_out, int out_size, void* d_ws, size_t ws_size,
                              hipStream_t stream) {
    const float* x      = (const float*)d_in[0];
    const int*   ei     = (const int*)d_in[1];
    const float* w1a    = (const float*)d_in[2];
    const float* b1a    = (const float*)d_in[3];
    const float* w2a    = (const float*)d_in[4];
    const float* b2a    = (const float*)d_in[5];
    const float* w1s    = (const float*)d_in[6];
    const float* b1s    = (const float*)d_in[7];
    const float* w2s    = (const float*)d_in[8];
    const float* b2s    = (const float*)d_in[9];
    const float* eps    = (const float*)d_in[10];
    const float* gammas = (const float*)d_in[11];
    const float* betas  = (const float*)d_in[12];
    const float* fcw    = (const float*)d_in[13];
    const float* fcb    = (const float*)d_in[14];
    float* out = (float*)d_out;

    int n = in_sizes[0];          // 50000
    int E = in_sizes[1] / 2;      // 1600000
    int npad = ((n + 63) / 64) * 64;
    int nblk = npad / 64;

    int nw = (n + WINSZ - 1) >> WINSH;      // 196 windows
    int NWB = nw * B1;
    int chunk = (((E + B1 - 1) / B1) + 3) & ~3;   // 4-aligned for int4 path
    int nbs2 = (NWB + 255) / 256;

    const int* src = ei;
    const int* dst = ei + E;

    char* p = (char*)d_ws;
    float* csrtmp  = (float*)p; p += (size_t)npad * HID * 4;   // CSR temps region
    float* hpre    = (float*)p; p += (size_t)npad * HID * 4;
    __half* hh16   = (__half*)p; p += (size_t)npad * HID * 2;
    __half* zh16   = (__half*)p; p += (size_t)npad * HID * 2;
    float* zscalar = (float*)p; p += (size_t)npad * 4;
    float* stats   = (float*)p; p += 4 * 128 * 4;
    unsigned short* whi = (unsigned short*)p; p += 7 * 4096 * 2;
    unsigned short* wlo = (unsigned short*)p; p += 7 * 4096 * 2;
    int* deg     = (int*)p; p += (size_t)n * 4;
    int* rowptr  = (int*)p; p += (size_t)n * 4;
    int* csr_src = (int*)p; p += (size_t)E * 4;

    // CSR-build temporaries live in csrtmp (dead after p4)
    int* ebuf     = (int*)csrtmp;
    int* cnt      = ebuf + E;
    int* cpart    = cnt + NWB;
    int* bsum     = cpart + NWB;
    int* blockoff = bsum + nbs2;

    // ---- prep (weights + stats zero + histogram) + CSR build ----
    prep_kernel<<<8 + B1, 256, 0, stream>>>(w2a, w1s, w2s, whi, wlo, stats,
                                            dst, cnt, E, nw, chunk);
    scan_a_kernel<<<nbs2, 256, 0, stream>>>(cnt, cpart, bsum, NWB);
    scan_b_kernel<<<1, 256, 0, stream>>>(bsum, blockoff, nbs2);
    p3_bucket_kernel<<<B1, 256, 0, stream>>>(src, dst, cpart, blockoff, ebuf, E, nw, chunk);
    p4_fine_kernel<<<nw, 256, 0, stream>>>(ebuf, cpart, blockoff, csr_src, rowptr, deg,
                                           E, n, nw);

    // ---- Layer 1 (1 -> 64 -> 64): writes fp16 mirror only ----
    gather1_kernel<<<(n + 3) / 4, 256, 0, stream>>>(x, rowptr, deg, csr_src, eps, zscalar, n);
    mlp_kernel<<<nblk, 256, 0, stream>>>(zh16, zscalar, w1a, b1a,
                                         whi, wlo, b1a /*unused*/,
                                         whi /*slot0=w2a*/, wlo, b2a,
                                         hpre, hh16, stats, n, 0,
                                         /*write_hpre=*/0, /*write_hh=*/1);

    // ---- Layers 2-4: gatherz (fp16 in/out) + MLP ----
    for (int l = 1; l <= 3; ++l) {
        gatherz_kernel<<<(n + 3) / 4, 256, 0, stream>>>(hh16,
                                                        stats + (l - 1) * 128,
                                                        gammas + (l - 1) * HID,
                                                        betas + (l - 1) * HID,
                                                        rowptr, deg, csr_src, eps, l, zh16, n);
        mlp_kernel<<<nblk, 256, 0, stream>>>(zh16, zscalar, w1a, b1a,
                                             whi + (size_t)l * 4096,
                                             wlo + (size_t)l * 4096,
                                             b1s + (size_t)(l - 1) * HID,
                                             whi + (size_t)(3 + l) * 4096,
                                             wlo + (size_t)(3 + l) * 4096,
                                             b2s + (size_t)(l - 1) * HID,
                                             hpre, hh16, stats + l * 128,
                                             n, 1,
                                             /*write_hpre=*/(l == 3) ? 1 : 0,
                                             /*write_hh=*/(l < 3) ? 1 : 0);
    }
    final_kernel<<<(n + 3) / 4, 256, 0, stream>>>(hpre, stats + 3 * 128,
                                                  gammas + 3 * HID, betas + 3 * HID,
                                                  fcw, fcb, out, n);
}